// Round 1
// baseline (280.696 us; speedup 1.0000x reference)
//
#include <hip/hip_runtime.h>
#include <stdint.h>

typedef uint32_t u32;
typedef uint64_t u64;

#define NB 4
#define NA 9
#define NH 34
#define NW 60
#define HW (NH*NW)            // 2040
#define NBOX (NA*HW)          // 18360
#define PRE_NMS 3000
#define POST_NMS 300
#define NBUCKET 4096
#define CAP 4096
#define NTH 1024
#define PER 18                // 18*1024 = 18432 >= 18360

// Anchor widths/heights: np.float64 values (s*sqrt(r), s/sqrt(r)) rounded to f32
// exactly as the reference's np.array(..., dtype=float32) does.
__device__ __constant__ float c_aw[9] = {
  45.254833995939045f, 64.0f,  90.50966799187808f,
  90.50966799187808f,  128.0f, 181.01933598375617f,
  181.01933598375617f, 256.0f, 362.03867196751233f };
__device__ __constant__ float c_ah[9] = {
  90.50966799187808f,  64.0f,  45.254833995939045f,
  181.01933598375617f, 128.0f, 90.50966799187808f,
  362.03867196751233f, 256.0f, 181.01933598375617f };

__global__ void __launch_bounds__(NTH)
rpn_proposal_kernel(const float* __restrict__ scores,
                    const float* __restrict__ deltas,
                    float* __restrict__ out)
{
  // LDS overlay:
  //  phase 1: [0,16K) hist u32[4096] | [16K,48K+16K) cand u64[4096] | [48K+1K..] sfx u32[1024]
  //  phase 2: [0,48000) boxes float4[3000]  (hist+cand dead by then)
  __shared__ __align__(16) char smem[16384 + 32768 + 4096];
  u32* s_hist = (u32*)smem;
  u64* s_cand = (u64*)(smem + 16384);
  u32* s_sfx  = (u32*)(smem + 16384 + 32768);
  float4* s_box = (float4*)smem;
  __shared__ u32 s_kept[POST_NMS];
  __shared__ u32 s_meta[4];   // 0:T(threshold bucket) 1:count 2:compact cnt 3:nk

  const int tid = threadIdx.x;
  const int b   = blockIdx.x;
  const float* sc = scores + b * NBOX;

  // ---- init ----
  for (int t = tid; t < NBUCKET; t += NTH) s_hist[t] = 0;
  if (tid < 4) s_meta[tid] = 0;
  __syncthreads();

  // ---- histogram of scores (uniform in [0,1)) ----
  for (int m = 0; m < PER; ++m) {
    int i = tid + m * NTH;
    if (i < NBOX) {
      float s = sc[i];
      int bk = (int)(s * (float)NBUCKET);
      bk = bk < 0 ? 0 : (bk > NBUCKET - 1 ? NBUCKET - 1 : bk);
      atomicAdd(&s_hist[bk], 1u);
    }
  }
  __syncthreads();

  // ---- group sums (4 buckets/group) + inclusive suffix scan over 1024 groups ----
  {
    u32 g = s_hist[4*tid] + s_hist[4*tid+1] + s_hist[4*tid+2] + s_hist[4*tid+3];
    s_sfx[tid] = g;
  }
  __syncthreads();
  for (int d = 1; d < NTH; d <<= 1) {
    u32 v = (tid + d < NTH) ? s_sfx[tid + d] : 0u;
    __syncthreads();
    s_sfx[tid] += v;
    __syncthreads();
  }

  // ---- find threshold bucket T: max t with suffix-count(t) >= PRE_NMS ----
  {
    u32 sg  = s_sfx[tid];
    u32 sgn = (tid < NTH - 1) ? s_sfx[tid + 1] : 0u;
    if (sg >= PRE_NMS && sgn < PRE_NMS) {      // exactly one thread
      u32 c = sgn;
      for (int t = 4 * tid + 3; t >= 4 * tid; --t) {
        c += s_hist[t];
        if (c >= PRE_NMS) { s_meta[0] = (u32)t; s_meta[1] = c; break; }
      }
    }
  }
  __syncthreads();
  const u32 T = s_meta[0];

  // ---- compact candidates (bucket >= T): count in [3000, ~3030] ----
  for (int m = 0; m < PER; ++m) {
    int i = tid + m * NTH;
    if (i < NBOX) {
      float s = sc[i];
      int bk = (int)(s * (float)NBUCKET);
      bk = bk < 0 ? 0 : (bk > NBUCKET - 1 ? NBUCKET - 1 : bk);
      if ((u32)bk >= T) {
        u32 pos = atomicAdd(&s_meta[2], 1u);
        if (pos < CAP) {
          // key: score bits high, ~idx low -> descending sort == top_k order
          // (ties broken by lower index, matching jax.lax.top_k)
          u64 key = ((u64)__float_as_uint(s) << 32) | (u32)(~(u32)i);
          s_cand[pos] = key;
        }
      }
    }
  }
  __syncthreads();
  {
    u32 C = s_meta[2]; if (C > CAP) C = CAP;
    for (u32 p = C + tid; p < CAP; p += NTH) s_cand[p] = 0ull;  // pad sinks to bottom
  }

  // ---- bitonic sort 4096 u64 keys, descending ----
  for (int kk = 2; kk <= CAP; kk <<= 1) {
    for (int j = kk >> 1; j > 0; j >>= 1) {
      __syncthreads();
      #pragma unroll
      for (int m = 0; m < 2; ++m) {
        int t = tid + m * NTH;                       // pair id 0..2047
        int i = ((t & ~(j - 1)) << 1) | (t & (j - 1));
        int p = i | j;
        u64 a  = s_cand[i];
        u64 bb = s_cand[p];
        bool desc = (i & kk) == 0;
        bool sw = desc ? (a < bb) : (a > bb);
        if (sw) { s_cand[i] = bb; s_cand[p] = a; }
      }
    }
  }
  __syncthreads();

  // ---- decode top-3000 boxes into registers, then overlay into LDS ----
  const float* dl = deltas + b * (4 * NA * HW);
  float4 bx[3];
  #pragma unroll
  for (int m = 0; m < 3; ++m) {
    int k = tid + m * NTH;
    if (k < PRE_NMS) {
      u64 key = s_cand[k];
      int idx = (int)(~(u32)key);
      int a = idx / HW;
      int r = idx - a * HW;
      int h = r / NW;
      int w = r - h * NW;
      const float* dp = dl + (4 * a) * HW + r;
      float tx = dp[0];
      float ty = dp[HW];
      float tw = dp[2 * HW];
      float th = dp[3 * HW];
      float aw = c_aw[a], ah = c_ah[a];
      float ctr_x = ((float)w + 0.5f) * 16.0f + tx * aw;
      float ctr_y = ((float)h + 0.5f) * 16.0f + ty * ah;
      float w1 = expf(tw) * aw;
      float h1 = expf(th) * ah;
      float x1 = ctr_x - 0.5f * w1;
      float y1 = ctr_y - 0.5f * h1;
      float x2 = x1 + w1;
      float y2 = y1 + h1;
      x1 = fminf(fmaxf(x1, 0.0f), 959.0f);
      x2 = fminf(fmaxf(x2, 0.0f), 959.0f);
      y1 = fminf(fmaxf(y1, 0.0f), 543.0f);
      y2 = fminf(fmaxf(y2, 0.0f), 543.0f);
      bx[m] = make_float4(x1, y1, x2, y2);
    }
  }
  __syncthreads();   // cand fully drained before overlay
  #pragma unroll
  for (int m = 0; m < 3; ++m) {
    int k = tid + m * NTH;
    if (k < PRE_NMS) s_box[k] = bx[m];
  }
  __syncthreads();

  // ---- greedy NMS on wave 0; kept boxes live in lane registers (5 slots x 64 lanes) ----
  if (tid < 64) {
    const int lane = tid;
    float4 kb[5];
    float  ka[5];
    int nk = 0;
    for (int i = 0; i < PRE_NMS; ++i) {
      if (nk >= POST_NMS) break;                 // only first 300 kept are emitted
      float4 c = s_box[i];                        // LDS broadcast
      float carea = (c.z - c.x) * (c.w - c.y);
      bool over = false;
      #pragma unroll
      for (int s = 0; s < 5; ++s) {
        if (s * 64 < nk) {                        // wave-uniform slot skip
          if (s * 64 + lane < nk) {
            float iw = fminf(kb[s].z, c.z) - fmaxf(kb[s].x, c.x);
            float ih = fminf(kb[s].w, c.w) - fmaxf(kb[s].y, c.y);
            iw = fmaxf(iw, 0.0f);
            ih = fmaxf(ih, 0.0f);
            float inter = iw * ih;
            float uni = ka[s] + carea - inter;
            over = over || (inter > 0.7f * fmaxf(uni, 1e-8f));
          }
        }
      }
      if (__ballot((int)over) == 0ull) {          // kept
        int s = nk >> 6, l = nk & 63;
        #pragma unroll
        for (int q = 0; q < 5; ++q)
          if (q == s && lane == l) { kb[q] = c; ka[q] = carea; }
        if (lane == 0) s_kept[nk] = (u32)i;
        ++nk;                                     // uniform across the wave
      }
    }
    if (lane == 0) s_meta[3] = (u32)nk;
  }
  __syncthreads();

  // ---- emit: first nk kept boxes in score order, zero-pad to 300 ----
  if (tid < POST_NMS) {
    u32 nk = s_meta[3];
    float4 v = make_float4(0.0f, 0.0f, 0.0f, 0.0f);
    if ((u32)tid < nk) v = s_box[s_kept[tid]];
    ((float4*)out)[b * POST_NMS + tid] = v;
  }
}

extern "C" void kernel_launch(void* const* d_in, const int* in_sizes, int n_in,
                              void* d_out, int out_size, void* d_ws, size_t ws_size,
                              hipStream_t stream) {
  const float* scores = (const float*)d_in[0];
  const float* deltas = (const float*)d_in[1];
  (void)in_sizes; (void)n_in; (void)d_ws; (void)ws_size; (void)out_size;
  rpn_proposal_kernel<<<dim3(NB), dim3(NTH), 0, stream>>>(scores, deltas, (float*)d_out);
}